// Round 7
// baseline (646.794 us; speedup 1.0000x reference)
//
#include <hip/hip_runtime.h>
#include <hip/hip_bf16.h>
#include <math.h>

#define NN 50000
#define EE 400000
#define EEN 450000       // edges + self-loops per type
#define TT 4
#define FD 128
#define RPS 50004        // rowp stride per type
#define NBKT 196         // buckets per type = ceil(NN/256)
#define BCAP 4096        // capacity per bucket (mean ~2300 incl self, max ~2600)
#define LOG2E 1.44269504f

typedef __attribute__((ext_vector_type(8))) short bf16x8;
typedef __attribute__((ext_vector_type(4))) float f32x4;

__device__ inline float bf2f(unsigned short u) {
  union { unsigned int i; float f; } x; x.i = ((unsigned int)u) << 16; return x.f;
}
__device__ inline unsigned short f2bf(float f) {
  __hip_bfloat16 h = __float2bfloat16(f);
  unsigned short u; __builtin_memcpy(&u, &h, 2); return u;
}
__device__ inline float blo(unsigned int u) {
  union { unsigned int i; float f; } x; x.i = u << 16; return x.f;
}
__device__ inline float bhi(unsigned int u) {
  union { unsigned int i; float f; } x; x.i = u & 0xFFFF0000u; return x.f;
}
__device__ inline float fexp2(float x) { return __builtin_amdgcn_exp2f(x); }
__device__ inline float sgn04(float a) {   // 0.4 * sign(a)
  union { float f; unsigned int i; } x; x.f = a;
  x.i = (x.i & 0x80000000u) | 0x3ECCCCCDu;
  return x.f;
}
// sum over each 8-lane group (8 independent groups per wave), pure DPP
__device__ inline float qsum8(float v) {
  v += __builtin_bit_cast(float, __builtin_amdgcn_update_dpp(
         0, __builtin_bit_cast(int, v), 0xB1, 0xF, 0xF, true));   // quad_perm xor1
  v += __builtin_bit_cast(float, __builtin_amdgcn_update_dpp(
         0, __builtin_bit_cast(int, v), 0x4E, 0xF, 0xF, true));   // quad_perm xor2
  v += __builtin_bit_cast(float, __builtin_amdgcn_update_dpp(
         0, __builtin_bit_cast(int, v), 0x141, 0xF, 0xF, true));  // row_half_mirror (xor4-in-8)
  return v;
}
__device__ inline void unpack8(const uint4 u, float* x) {
  x[0] = blo(u.x); x[1] = bhi(u.x); x[2] = blo(u.y); x[3] = bhi(u.y);
  x[4] = blo(u.z); x[5] = bhi(u.z); x[6] = blo(u.w); x[7] = bhi(u.w);
}

// ---------- weight pack: W[k][c] f32 -> bf16 fragments in MFMA order ----------
__global__ void k_cvtW(const float* __restrict__ Wl1, const float* __restrict__ Wr1,
                       const float* __restrict__ Wl2, const float* __restrict__ Wr2,
                       unsigned short* __restrict__ Bpack) {
  const int idx = blockIdx.x * 256 + threadIdx.x;      // 2*4*2*16384 = 262144
  const int R = idx >> 14;
  const int kc = idx & 16383;
  const int lr = R & 1, t = (R >> 1) & 3, layer = R >> 3;
  const float* W = layer ? (lr ? Wr2 : Wl2) : (lr ? Wr1 : Wl1);
  const float v = W[t * 16384 + kc];
  const int k = kc >> 7, c = kc & 127;
  const int nt = c >> 4, ks = k >> 5, g = (k >> 3) & 3, j = k & 7;
  const int lane = g * 16 + (c & 15);
  Bpack[(size_t)R * 16384 + ((nt * 4 + ks) * 64 + lane) * 8 + j] = f2bf(v);
}

// ---------- A split: f32 -> (hi, lo) bf16 ----------
__global__ void k_cvtA(const float* __restrict__ src, unsigned short* __restrict__ ahi,
                       unsigned short* __restrict__ alo) {
  const int idx = blockIdx.x * 256 + threadIdx.x;      // NN*FD/4 = 1,600,000
  float4 v = ((const float4*)src)[idx];
  const unsigned short h0 = f2bf(v.x), h1 = f2bf(v.y), h2 = f2bf(v.z), h3 = f2bf(v.w);
  const unsigned short l0 = f2bf(v.x - bf2f(h0)), l1 = f2bf(v.y - bf2f(h1));
  const unsigned short l2 = f2bf(v.z - bf2f(h2)), l3 = f2bf(v.w - bf2f(h3));
  uint2 hv, lv;
  hv.x = (unsigned)h0 | ((unsigned)h1 << 16); hv.y = (unsigned)h2 | ((unsigned)h3 << 16);
  lv.x = (unsigned)l0 | ((unsigned)l1 << 16); lv.y = (unsigned)l2 | ((unsigned)l3 << 16);
  ((uint2*)ahi)[idx] = hv;
  ((uint2*)alo)[idx] = lv;
}

// ---------- MFMA GEMM, all 4 types in one dispatch: grid (782, TT) ----------
__global__ __launch_bounds__(128) void k_gemm4(
    const unsigned short* __restrict__ Ahi, const unsigned short* __restrict__ Alo,
    const unsigned short* __restrict__ Bbase,
    unsigned short* __restrict__ xl4, unsigned short* __restrict__ xr4) {
  const int t = blockIdx.y;
  const unsigned short* Bpt = Bbase + (size_t)t * 2 * 16384;
  unsigned short* xl = xl4 + (size_t)t * NN * FD;
  unsigned short* xr = xr4 + (size_t)t * NN * FD;
  const int tid = threadIdx.x;
  const int lane = tid & 63;
  const int w = tid >> 6;
  const int rh = lane & 15, g = lane >> 4;
  const int m0 = blockIdx.x * 64 + w * 32;
  f32x4 acc[2][16];
  #pragma unroll
  for (int a = 0; a < 2; ++a)
    #pragma unroll
    for (int b = 0; b < 16; ++b) acc[a][b] = (f32x4){0.f, 0.f, 0.f, 0.f};
  int r0 = m0 + rh;      if (r0 > NN - 1) r0 = NN - 1;
  int r1 = m0 + 16 + rh; if (r1 > NN - 1) r1 = NN - 1;
  #pragma unroll
  for (int ks = 0; ks < 4; ++ks) {
    const int ko = ks * 32 + g * 8;
    const bf16x8 ah0 = *(const bf16x8*)(Ahi + (size_t)r0 * FD + ko);
    const bf16x8 al0 = *(const bf16x8*)(Alo + (size_t)r0 * FD + ko);
    const bf16x8 ah1 = *(const bf16x8*)(Ahi + (size_t)r1 * FD + ko);
    const bf16x8 al1 = *(const bf16x8*)(Alo + (size_t)r1 * FD + ko);
    #pragma unroll
    for (int nt = 0; nt < 16; ++nt) {
      const bf16x8 b = *(const bf16x8*)(Bpt + (nt >> 3) * 16384 +
                                        (((nt & 7) * 4 + ks) * 64 + lane) * 8);
      acc[0][nt] = __builtin_amdgcn_mfma_f32_16x16x32_bf16(ah0, b, acc[0][nt], 0, 0, 0);
      acc[0][nt] = __builtin_amdgcn_mfma_f32_16x16x32_bf16(al0, b, acc[0][nt], 0, 0, 0);
      acc[1][nt] = __builtin_amdgcn_mfma_f32_16x16x32_bf16(ah1, b, acc[1][nt], 0, 0, 0);
      acc[1][nt] = __builtin_amdgcn_mfma_f32_16x16x32_bf16(al1, b, acc[1][nt], 0, 0, 0);
    }
  }
  #pragma unroll
  for (int mt = 0; mt < 2; ++mt)
    #pragma unroll
    for (int nt = 0; nt < 16; ++nt) {
      unsigned short* op = (nt < 8) ? xl : xr;
      const int cb = (nt & 7) * 16 + rh;
      #pragma unroll
      for (int r = 0; r < 4; ++r) {
        const int row = m0 + mt * 16 + g * 4 + r;   // m89-verified C/D mapping
        if (row < NN) op[(size_t)row * FD + cb] = f2bf(acc[mt][nt][r]);
      }
    }
}

// ---------- CSR build (self-loops appended as real edges) ----------
__global__ __launch_bounds__(256) void k_bucket(const int* __restrict__ ei,
                                                int* __restrict__ bcur,
                                                unsigned int* __restrict__ ebuf) {
  __shared__ int lcnt[NBKT], lbase[NBKT];
  const int t = blockIdx.y, tid = threadIdx.x;
  const int cbase = blockIdx.x * 4096;
  if (tid < NBKT) lcnt[tid] = 0;
  __syncthreads();
  const int* srcp = ei + (size_t)t * 2 * EE;
  const int* dstp = srcp + EE;
  unsigned int pk[16]; int rk[16];
  #pragma unroll
  for (int i = 0; i < 16; ++i) {
    const int e = cbase + i * 256 + tid;
    rk[i] = -1;
    if (e < EEN) {
      int s, dd;
      if (e < EE) { s = srcp[e]; dd = dstp[e]; }
      else        { s = dd = e - EE; }           // self-loop
      const int b = dd >> 8;
      pk[i] = ((unsigned)dd << 16) | (unsigned)s;
      rk[i] = (atomicAdd(&lcnt[b], 1) << 8) | b;
    }
  }
  __syncthreads();
  if (tid < NBKT && lcnt[tid] > 0) lbase[tid] = atomicAdd(&bcur[t * NBKT + tid], lcnt[tid]);
  __syncthreads();
  #pragma unroll
  for (int i = 0; i < 16; ++i) {
    if (rk[i] >= 0) {
      const int b = rk[i] & 255, r = rk[i] >> 8;
      ebuf[((size_t)t * NBKT + b) * BCAP + lbase[b] + r] = pk[i];
    }
  }
}

__global__ void k_bktscan(const int* __restrict__ bcur, int* __restrict__ bbase) {
  __shared__ int s[TT * NBKT];
  const int tid = threadIdx.x;   // 1024
  int v0 = 0;
  if (tid < TT * NBKT) { v0 = bcur[tid]; s[tid] = v0; }
  __syncthreads();
  #pragma unroll
  for (int off = 1; off < NBKT; off <<= 1) {
    int a = 0;
    if (tid < TT * NBKT && (tid % NBKT) >= off) a = s[tid - off];
    __syncthreads();
    if (tid < TT * NBKT) s[tid] += a;
    __syncthreads();
  }
  if (tid < TT * NBKT) bbase[tid] = s[tid] - v0;   // exclusive within type
}

__global__ __launch_bounds__(256) void k_scatter3(const unsigned int* __restrict__ ebuf,
                                                  const int* __restrict__ bcur,
                                                  const int* __restrict__ bbase,
                                                  int* __restrict__ rowp,
                                                  int* __restrict__ col) {
  __shared__ int lc[256], sc[256];
  const int b = blockIdx.x, t = blockIdx.y, tid = threadIdx.x;
  const int d0 = b << 8;
  const int nd = (NN - d0 < 256) ? (NN - d0) : 256;
  const int cnt = bcur[t * NBKT + b];
  const int base = bbase[t * NBKT + b];
  const unsigned int* eb = ebuf + ((size_t)t * NBKT + b) * BCAP;
  lc[tid] = 0;
  __syncthreads();
  for (int j = tid; j < cnt; j += 256) {
    atomicAdd(&lc[(eb[j] >> 16) - d0], 1);
  }
  __syncthreads();
  const int v = lc[tid];
  sc[tid] = v;
  __syncthreads();
  #pragma unroll
  for (int off = 1; off < 256; off <<= 1) {
    const int a = (tid >= off) ? sc[tid - off] : 0;
    __syncthreads();
    sc[tid] += a;
    __syncthreads();
  }
  const int excl = base + sc[tid] - v;
  if (tid < nd) rowp[(size_t)t * RPS + d0 + tid] = excl;
  if (b == NBKT - 1 && tid == 0) rowp[(size_t)t * RPS + NN] = EEN;
  lc[tid] = excl;          // becomes the scatter cursor
  __syncthreads();
  for (int j = tid; j < cnt; j += 256) {
    const unsigned int u = eb[j];
    const int pos = atomicAdd(&lc[(u >> 16) - d0], 1);
    col[(size_t)t * EEN + pos] = (int)(u & 0xFFFF);
  }
}

// ---------- GATv2 aggregation v3: one wave per dst -------------------------
// 64 lanes = 8 groups of 8: group g = (edge-slot g>>1, head g&1).
// Lane owns 8 channels: ch = head*64 + sub*8 .. +7 (sub = lane&7) -> 16B/lane.
// 4 edges in flight per iteration; NO max tracking (scores provably bounded,
// raw exp2 accumulation is overflow-safe in f32); self-loops are CSR edges.
// Per type: den reduced across slots (2 shfl), acc stays per-slot, folded into
// per-slot o via acc*rcp(den); one cross-slot o reduce per dst at the end.
// mode 0: relu + bf16 hi/lo split into ahi/alo; mode 1: f32 h row out.
__global__ __launch_bounds__(256) void k_agg6(
    const unsigned short* __restrict__ xl4, const unsigned short* __restrict__ xr4,
    const int* __restrict__ col, const int* __restrict__ rowp,
    const float* __restrict__ att, const float* __restrict__ bias,
    unsigned short* __restrict__ ahi, unsigned short* __restrict__ alo,
    float* __restrict__ hout, const int mode) {
  const int lane = threadIdx.x & 63;
  const int d = blockIdx.x * 4 + (threadIdx.x >> 6);   // 12500*4 = 50000 exact
  const int g = lane >> 3;
  const int slot = g >> 1, head = g & 1, sub = lane & 7;
  const int laneoff = head * 128 + sub * 16;           // byte offset in 256B row
  const int choff = head * 64 + sub * 8;               // float idx for att/bias
  float o[8];
  #pragma unroll
  for (int j = 0; j < 8; ++j) o[j] = 0.f;
  #pragma unroll
  for (int t = 0; t < TT; ++t) {
    const char* xlt = (const char*)xl4 + (size_t)t * NN * 256 + laneoff;
    const char* xrt = (const char*)xr4 + (size_t)t * NN * 256 + laneoff;
    const int* colt = col + (size_t)t * EEN;
    const float4 a0 = *(const float4*)(att + t * FD + choff);
    const float4 a1 = *(const float4*)(att + t * FD + choff + 4);
    float av[8] = {a0.x, a0.y, a0.z, a0.w, a1.x, a1.y, a1.z, a1.w};
    const uint4 ur = *(const uint4*)(xrt + (size_t)d * 256);
    float xrv[8]; unpack8(ur, xrv);
    float sa[8], axr[8];
    #pragma unroll
    for (int j = 0; j < 8; ++j) {
      av[j] *= LOG2E; sa[j] = sgn04(av[j]); axr[j] = av[j] * xrv[j];
    }
    float den = 0.f, acc[8];
    #pragma unroll
    for (int j = 0; j < 8; ++j) acc[j] = 0.f;
    const int beg = rowp[t * RPS + d];
    const int end = rowp[t * RPS + d + 1];
    for (int e0 = beg; e0 < end; e0 += 4) {
      const int e = e0 + slot;
      const bool act = e < end;
      const int s = colt[act ? e : end - 1];
      const uint4 u = *(const uint4*)(xlt + ((size_t)((unsigned)s << 8)));
      float x[8]; unpack8(u, x);
      float s06 = 0.f, sr = 0.f;
      #pragma unroll
      for (int j = 0; j < 8; ++j) {
        const float q = fmaf(av[j], x[j], axr[j]);
        s06 += q;
        sr = fmaf(sa[j], fabsf(q), sr);
      }
      const float c = qsum8(fmaf(0.6f, s06, sr));
      const float w = act ? fexp2(c) : 0.f;
      den += w;
      #pragma unroll
      for (int j = 0; j < 8; ++j) acc[j] = fmaf(w, x[j], acc[j]);
    }
    den += __shfl_xor(den, 16);
    den += __shfl_xor(den, 32);
    const float rden = __builtin_amdgcn_rcpf(den);
    #pragma unroll
    for (int j = 0; j < 8; ++j) o[j] = fmaf(acc[j], rden, o[j]);
  }
  #pragma unroll
  for (int j = 0; j < 8; ++j) {
    o[j] += __shfl_xor(o[j], 16);
    o[j] += __shfl_xor(o[j], 32);
  }
  #pragma unroll
  for (int t = 0; t < TT; ++t) {
    const float4 b0 = *(const float4*)(bias + t * FD + choff);
    const float4 b1 = *(const float4*)(bias + t * FD + choff + 4);
    o[0] += b0.x; o[1] += b0.y; o[2] += b0.z; o[3] += b0.w;
    o[4] += b1.x; o[5] += b1.y; o[6] += b1.z; o[7] += b1.w;
  }
  if (lane < 16) {    // groups 0,1 cover head0+head1 = full 128-ch row
    if (mode == 0) {
      unsigned short hs[8], ls[8];
      #pragma unroll
      for (int j = 0; j < 8; ++j) {
        const float r = fmaxf(o[j], 0.f);
        hs[j] = f2bf(r);
        ls[j] = f2bf(r - bf2f(hs[j]));
      }
      uint4 hv, lv;
      hv.x = (unsigned)hs[0] | ((unsigned)hs[1] << 16);
      hv.y = (unsigned)hs[2] | ((unsigned)hs[3] << 16);
      hv.z = (unsigned)hs[4] | ((unsigned)hs[5] << 16);
      hv.w = (unsigned)hs[6] | ((unsigned)hs[7] << 16);
      lv.x = (unsigned)ls[0] | ((unsigned)ls[1] << 16);
      lv.y = (unsigned)ls[2] | ((unsigned)ls[3] << 16);
      lv.z = (unsigned)ls[4] | ((unsigned)ls[5] << 16);
      lv.w = (unsigned)ls[6] | ((unsigned)ls[7] << 16);
      *(uint4*)((char*)ahi + (size_t)d * 256 + laneoff) = hv;
      *(uint4*)((char*)alo + (size_t)d * 256 + laneoff) = lv;
    } else {
      *(float4*)(hout + (size_t)d * FD + choff) = make_float4(o[0], o[1], o[2], o[3]);
      *(float4*)(hout + (size_t)d * FD + choff + 4) = make_float4(o[4], o[5], o[6], o[7]);
    }
  }
}

// ---------- MLP head (relu on h fused): thread per dst ----------
__global__ __launch_bounds__(256) void k_mlp(const float* __restrict__ h,
                                             const float* __restrict__ W1,
                                             const float* __restrict__ b1,
                                             const float* __restrict__ W2,
                                             const float* __restrict__ b2,
                                             float* __restrict__ out) {
  __shared__ float sW1[128 * 8];
  __shared__ float sW2[8 * 10];
  __shared__ float sb1[8], sb2[10];
  for (int i = threadIdx.x; i < 1024; i += 256) sW1[i] = W1[i];
  if (threadIdx.x < 80) sW2[threadIdx.x] = W2[threadIdx.x];
  if (threadIdx.x < 8)  sb1[threadIdx.x] = b1[threadIdx.x];
  if (threadIdx.x < 10) sb2[threadIdx.x] = b2[threadIdx.x];
  __syncthreads();
  const int n = blockIdx.x * 256 + threadIdx.x;
  if (n >= NN) return;
  const float* hn = h + (size_t)n * FD;
  float z[8];
  #pragma unroll
  for (int j = 0; j < 8; ++j) z[j] = sb1[j];
  for (int k = 0; k < FD; k += 4) {
    float4 hv = *(const float4*)(hn + k);
    hv.x = fmaxf(hv.x, 0.f); hv.y = fmaxf(hv.y, 0.f);
    hv.z = fmaxf(hv.z, 0.f); hv.w = fmaxf(hv.w, 0.f);
    #pragma unroll
    for (int j = 0; j < 8; ++j) {
      z[j] += hv.x * sW1[(k + 0) * 8 + j] + hv.y * sW1[(k + 1) * 8 + j]
            + hv.z * sW1[(k + 2) * 8 + j] + hv.w * sW1[(k + 3) * 8 + j];
    }
  }
  #pragma unroll
  for (int j = 0; j < 8; ++j) z[j] = fmaxf(z[j], 0.f);
  float o[10];
  #pragma unroll
  for (int c = 0; c < 10; ++c) o[c] = sb2[c];
  #pragma unroll
  for (int j = 0; j < 8; ++j)
    #pragma unroll
    for (int c = 0; c < 10; ++c) o[c] += z[j] * sW2[j * 10 + c];
  float* op = out + (size_t)n * 10;
  #pragma unroll
  for (int c = 0; c < 10; ++c) op[c] = o[c];
}

extern "C" void kernel_launch(void* const* d_in, const int* in_sizes, int n_in,
                              void* d_out, int out_size, void* d_ws, size_t ws_size,
                              hipStream_t stream) {
  const float* x    = (const float*)d_in[0];
  const int*   ei   = (const int*)d_in[1];
  const float* Wl1  = (const float*)d_in[2];
  const float* Wr1  = (const float*)d_in[3];
  const float* att1 = (const float*)d_in[4];
  const float* b1   = (const float*)d_in[5];
  const float* Wl2  = (const float*)d_in[6];
  const float* Wr2  = (const float*)d_in[7];
  const float* att2 = (const float*)d_in[8];
  const float* b2   = (const float*)d_in[9];
  const float* Wi1  = (const float*)d_in[10];
  const float* bi1  = (const float*)d_in[11];
  const float* Wi2  = (const float*)d_in[12];
  const float* bi2  = (const float*)d_in[13];
  float* out = (float*)d_out;

  char* ws = (char*)d_ws;
  size_t off = 0;
  auto alloc = [&](size_t bytes) {
    void* p = ws + off;
    off = (off + bytes + 255) & ~(size_t)255;
    return p;
  };
  unsigned short* xl4   = (unsigned short*)alloc((size_t)TT * NN * FD * 2); // 51.2 MB
  unsigned short* xr4   = (unsigned short*)alloc((size_t)TT * NN * FD * 2); // 51.2 MB
  unsigned short* Ahi   = (unsigned short*)alloc((size_t)NN * FD * 2);      // 12.8 MB
  unsigned short* Alo   = (unsigned short*)alloc((size_t)NN * FD * 2);      // 12.8 MB (contiguous)
  unsigned short* Bpack = (unsigned short*)alloc((size_t)2 * TT * 2 * 16384 * 2); // 0.5 MB
  int*            col   = (int*)alloc((size_t)TT * EEN * 4);                // 7.2 MB
  int*            rowp  = (int*)alloc((size_t)TT * RPS * 4);                // 0.8 MB
  int*            bcur  = (int*)alloc((size_t)TT * NBKT * 4);
  int*            bbase = (int*)alloc((size_t)TT * NBKT * 4);
  unsigned int*   ebuf  = (unsigned int*)alloc((size_t)TT * NBKT * BCAP * 4); // 12.85 MB
  // h2 (f32, 25.6 MB) aliases Ahi+Alo (both dead after layer-2 k_gemm4).
  float* h2 = (float*)Ahi;

  // --- CSR build (shared by both layers; self-loops included) ---
  hipMemsetAsync(bcur, 0, (size_t)TT * NBKT * 4, stream);
  k_cvtW<<<1024, 256, 0, stream>>>(Wl1, Wr1, Wl2, Wr2, Bpack);
  k_bucket<<<dim3(110, TT), 256, 0, stream>>>(ei, bcur, ebuf);
  k_bktscan<<<1, 1024, 0, stream>>>(bcur, bbase);
  k_scatter3<<<dim3(NBKT, TT), 256, 0, stream>>>(ebuf, bcur, bbase, rowp, col);

  // --- layer 1 ---
  k_cvtA<<<6250, 256, 0, stream>>>(x, Ahi, Alo);
  k_gemm4<<<dim3(782, TT), 128, 0, stream>>>(Ahi, Alo, Bpack, xl4, xr4);
  k_agg6<<<12500, 256, 0, stream>>>(xl4, xr4, col, rowp, att1, b1,
                                    Ahi, Alo, nullptr, 0);
  // --- layer 2 ---
  k_gemm4<<<dim3(782, TT), 128, 0, stream>>>(Ahi, Alo, Bpack + (size_t)TT * 2 * 16384,
                                             xl4, xr4);
  k_agg6<<<12500, 256, 0, stream>>>(xl4, xr4, col, rowp, att2, b2,
                                    nullptr, nullptr, h2, 1);
  // --- MLP head ---
  k_mlp<<<(NN + 255) / 256, 256, 0, stream>>>(h2, Wi1, bi1, Wi2, bi2, out);
}

// Round 10
// 533.222 us; speedup vs baseline: 1.2130x; 1.2130x over previous
//
#include <hip/hip_runtime.h>
#include <hip/hip_bf16.h>
#include <math.h>

#define NN 50000
#define EE 400000
#define EEN 450000       // edges + self-loops per type
#define TT 4
#define FD 128
#define RPS 50004        // rowp stride per type
#define NBKT 196         // buckets per type = ceil(NN/256)
#define BCAP 4096        // capacity per bucket (mean ~2300 incl self, max ~2600)
#define LOG2E 1.44269504f

typedef __attribute__((ext_vector_type(8))) short bf16x8;
typedef __attribute__((ext_vector_type(4))) float f32x4;

__device__ inline float bf2f(unsigned short u) {
  union { unsigned int i; float f; } x; x.i = ((unsigned int)u) << 16; return x.f;
}
__device__ inline unsigned short f2bf(float f) {
  __hip_bfloat16 h = __float2bfloat16(f);
  unsigned short u; __builtin_memcpy(&u, &h, 2); return u;
}
__device__ inline float blo(unsigned int u) {
  union { unsigned int i; float f; } x; x.i = u << 16; return x.f;
}
__device__ inline float bhi(unsigned int u) {
  union { unsigned int i; float f; } x; x.i = u & 0xFFFF0000u; return x.f;
}
__device__ inline float fexp2(float x) { return __builtin_amdgcn_exp2f(x); }
__device__ inline float sgn04(float a) {   // 0.4 * sign(a)
  union { float f; unsigned int i; } x; x.f = a;
  x.i = (x.i & 0x80000000u) | 0x3ECCCCCDu;
  return x.f;
}
// sum over each 32-lane half (verified in round 5): 4 DPP + 1 swizzle(xor16)
__device__ inline float qsum32(float v) {
  v += __builtin_bit_cast(float, __builtin_amdgcn_update_dpp(
         0, __builtin_bit_cast(int, v), 0xB1, 0xF, 0xF, true));   // quad_perm xor1
  v += __builtin_bit_cast(float, __builtin_amdgcn_update_dpp(
         0, __builtin_bit_cast(int, v), 0x4E, 0xF, 0xF, true));   // quad_perm xor2
  v += __builtin_bit_cast(float, __builtin_amdgcn_update_dpp(
         0, __builtin_bit_cast(int, v), 0x141, 0xF, 0xF, true));  // row_half_mirror (xor4)
  v += __builtin_bit_cast(float, __builtin_amdgcn_update_dpp(
         0, __builtin_bit_cast(int, v), 0x140, 0xF, 0xF, true));  // row_mirror (xor8)
  v += __builtin_bit_cast(float, __builtin_amdgcn_ds_swizzle(
         __builtin_bit_cast(int, v), 0x401F));                    // xor16 (within 32)
  return v;
}

// ---------- weight pack: W[k][c] f32 -> bf16 fragments in MFMA order ----------
__global__ void k_cvtW(const float* __restrict__ Wl1, const float* __restrict__ Wr1,
                       const float* __restrict__ Wl2, const float* __restrict__ Wr2,
                       unsigned short* __restrict__ Bpack) {
  const int idx = blockIdx.x * 256 + threadIdx.x;      // 2*4*2*16384 = 262144
  const int R = idx >> 14;
  const int kc = idx & 16383;
  const int lr = R & 1, t = (R >> 1) & 3, layer = R >> 3;
  const float* W = layer ? (lr ? Wr2 : Wl2) : (lr ? Wr1 : Wl1);
  const float v = W[t * 16384 + kc];
  const int k = kc >> 7, c = kc & 127;
  const int nt = c >> 4, ks = k >> 5, g = (k >> 3) & 3, j = k & 7;
  const int lane = g * 16 + (c & 15);
  Bpack[(size_t)R * 16384 + ((nt * 4 + ks) * 64 + lane) * 8 + j] = f2bf(v);
}

// ---------- A split: f32 -> (hi, lo) bf16 ----------
__global__ void k_cvtA(const float* __restrict__ src, unsigned short* __restrict__ ahi,
                       unsigned short* __restrict__ alo) {
  const int idx = blockIdx.x * 256 + threadIdx.x;      // NN*FD/4 = 1,600,000
  float4 v = ((const float4*)src)[idx];
  const unsigned short h0 = f2bf(v.x), h1 = f2bf(v.y), h2 = f2bf(v.z), h3 = f2bf(v.w);
  const unsigned short l0 = f2bf(v.x - bf2f(h0)), l1 = f2bf(v.y - bf2f(h1));
  const unsigned short l2 = f2bf(v.z - bf2f(h2)), l3 = f2bf(v.w - bf2f(h3));
  uint2 hv, lv;
  hv.x = (unsigned)h0 | ((unsigned)h1 << 16); hv.y = (unsigned)h2 | ((unsigned)h3 << 16);
  lv.x = (unsigned)l0 | ((unsigned)l1 << 16); lv.y = (unsigned)l2 | ((unsigned)l3 << 16);
  ((uint2*)ahi)[idx] = hv;
  ((uint2*)alo)[idx] = lv;
}

// ---------- MFMA GEMM, all 4 types in one dispatch: grid (782, TT) ----------
__global__ __launch_bounds__(128) void k_gemm4(
    const unsigned short* __restrict__ Ahi, const unsigned short* __restrict__ Alo,
    const unsigned short* __restrict__ Bbase,
    unsigned short* __restrict__ xl4, unsigned short* __restrict__ xr4) {
  const int t = blockIdx.y;
  const unsigned short* Bpt = Bbase + (size_t)t * 2 * 16384;
  unsigned short* xl = xl4 + (size_t)t * NN * FD;
  unsigned short* xr = xr4 + (size_t)t * NN * FD;
  const int tid = threadIdx.x;
  const int lane = tid & 63;
  const int w = tid >> 6;
  const int rh = lane & 15, g = lane >> 4;
  const int m0 = blockIdx.x * 64 + w * 32;
  f32x4 acc[2][16];
  #pragma unroll
  for (int a = 0; a < 2; ++a)
    #pragma unroll
    for (int b = 0; b < 16; ++b) acc[a][b] = (f32x4){0.f, 0.f, 0.f, 0.f};
  int r0 = m0 + rh;      if (r0 > NN - 1) r0 = NN - 1;
  int r1 = m0 + 16 + rh; if (r1 > NN - 1) r1 = NN - 1;
  #pragma unroll
  for (int ks = 0; ks < 4; ++ks) {
    const int ko = ks * 32 + g * 8;
    const bf16x8 ah0 = *(const bf16x8*)(Ahi + (size_t)r0 * FD + ko);
    const bf16x8 al0 = *(const bf16x8*)(Alo + (size_t)r0 * FD + ko);
    const bf16x8 ah1 = *(const bf16x8*)(Ahi + (size_t)r1 * FD + ko);
    const bf16x8 al1 = *(const bf16x8*)(Alo + (size_t)r1 * FD + ko);
    #pragma unroll
    for (int nt = 0; nt < 16; ++nt) {
      const bf16x8 b = *(const bf16x8*)(Bpt + (nt >> 3) * 16384 +
                                        (((nt & 7) * 4 + ks) * 64 + lane) * 8);
      acc[0][nt] = __builtin_amdgcn_mfma_f32_16x16x32_bf16(ah0, b, acc[0][nt], 0, 0, 0);
      acc[0][nt] = __builtin_amdgcn_mfma_f32_16x16x32_bf16(al0, b, acc[0][nt], 0, 0, 0);
      acc[1][nt] = __builtin_amdgcn_mfma_f32_16x16x32_bf16(ah1, b, acc[1][nt], 0, 0, 0);
      acc[1][nt] = __builtin_amdgcn_mfma_f32_16x16x32_bf16(al1, b, acc[1][nt], 0, 0, 0);
    }
  }
  #pragma unroll
  for (int mt = 0; mt < 2; ++mt)
    #pragma unroll
    for (int nt = 0; nt < 16; ++nt) {
      unsigned short* op = (nt < 8) ? xl : xr;
      const int cb = (nt & 7) * 16 + rh;
      #pragma unroll
      for (int r = 0; r < 4; ++r) {
        const int row = m0 + mt * 16 + g * 4 + r;   // m89-verified C/D mapping
        if (row < NN) op[(size_t)row * FD + cb] = f2bf(acc[mt][nt][r]);
      }
    }
}

// ---------- CSR build (self-loops appended as real edges) ----------
__global__ __launch_bounds__(256) void k_bucket(const int* __restrict__ ei,
                                                int* __restrict__ bcur,
                                                unsigned int* __restrict__ ebuf) {
  __shared__ int lcnt[NBKT], lbase[NBKT];
  const int t = blockIdx.y, tid = threadIdx.x;
  const int cbase = blockIdx.x * 4096;
  if (tid < NBKT) lcnt[tid] = 0;
  __syncthreads();
  const int* srcp = ei + (size_t)t * 2 * EE;
  const int* dstp = srcp + EE;
  unsigned int pk[16]; int rk[16];
  #pragma unroll
  for (int i = 0; i < 16; ++i) {
    const int e = cbase + i * 256 + tid;
    rk[i] = -1;
    if (e < EEN) {
      int s, dd;
      if (e < EE) { s = srcp[e]; dd = dstp[e]; }
      else        { s = dd = e - EE; }           // self-loop
      const int b = dd >> 8;
      pk[i] = ((unsigned)dd << 16) | (unsigned)s;
      rk[i] = (atomicAdd(&lcnt[b], 1) << 8) | b;
    }
  }
  __syncthreads();
  if (tid < NBKT && lcnt[tid] > 0) lbase[tid] = atomicAdd(&bcur[t * NBKT + tid], lcnt[tid]);
  __syncthreads();
  #pragma unroll
  for (int i = 0; i < 16; ++i) {
    if (rk[i] >= 0) {
      const int b = rk[i] & 255, r = rk[i] >> 8;
      ebuf[((size_t)t * NBKT + b) * BCAP + lbase[b] + r] = pk[i];
    }
  }
}

__global__ void k_bktscan(const int* __restrict__ bcur, int* __restrict__ bbase) {
  __shared__ int s[TT * NBKT];
  const int tid = threadIdx.x;   // 1024
  int v0 = 0;
  if (tid < TT * NBKT) { v0 = bcur[tid]; s[tid] = v0; }
  __syncthreads();
  #pragma unroll
  for (int off = 1; off < NBKT; off <<= 1) {
    int a = 0;
    if (tid < TT * NBKT && (tid % NBKT) >= off) a = s[tid - off];
    __syncthreads();
    if (tid < TT * NBKT) s[tid] += a;
    __syncthreads();
  }
  if (tid < TT * NBKT) bbase[tid] = s[tid] - v0;   // exclusive within type
}

__global__ __launch_bounds__(256) void k_scatter3(const unsigned int* __restrict__ ebuf,
                                                  const int* __restrict__ bcur,
                                                  const int* __restrict__ bbase,
                                                  int* __restrict__ rowp,
                                                  int* __restrict__ col) {
  __shared__ int lc[256], sc[256];
  const int b = blockIdx.x, t = blockIdx.y, tid = threadIdx.x;
  const int d0 = b << 8;
  const int nd = (NN - d0 < 256) ? (NN - d0) : 256;
  const int cnt = bcur[t * NBKT + b];
  const int base = bbase[t * NBKT + b];
  const unsigned int* eb = ebuf + ((size_t)t * NBKT + b) * BCAP;
  lc[tid] = 0;
  __syncthreads();
  for (int j = tid; j < cnt; j += 256) {
    atomicAdd(&lc[(eb[j] >> 16) - d0], 1);
  }
  __syncthreads();
  const int v = lc[tid];
  sc[tid] = v;
  __syncthreads();
  #pragma unroll
  for (int off = 1; off < 256; off <<= 1) {
    const int a = (tid >= off) ? sc[tid - off] : 0;
    __syncthreads();
    sc[tid] += a;
    __syncthreads();
  }
  const int excl = base + sc[tid] - v;
  if (tid < nd) rowp[(size_t)t * RPS + d0 + tid] = excl;
  if (b == NBKT - 1 && tid == 0) rowp[(size_t)t * RPS + NN] = EEN;
  lc[tid] = excl;          // becomes the scatter cursor
  __syncthreads();
  for (int j = tid; j < cnt; j += 256) {
    const unsigned int u = eb[j];
    const int pos = atomicAdd(&lc[(u >> 16) - d0], 1);
    col[(size_t)t * EEN + pos] = (int)(u & 0xFFFF);
  }
}

// ---------- GATv2 aggregation v4: one wave per dst, edge-serial, 4B/lane ----
// Lanes 0-31 = head0 (2 ch/lane), 32-63 = head1. Per-head score via qsum32;
// den is uniform per half (no reduction). No max tracking (scores bounded,
// exp2-domain f32 accumulation overflow-safe). Self-loops are CSR edges.
// Gathers: 4 edge indices read by lanes 0-3, readlane -> SGPR base -> saddr
// loads; next batch's col+gathers issued before processing current (dbuf).
// mode 0: relu + bf16 hi/lo split into ahi/alo; mode 1: f32 h row out.
__global__ __launch_bounds__(256) void k_agg7(
    const unsigned short* __restrict__ xl4, const unsigned short* __restrict__ xr4,
    const int* __restrict__ col, const int* __restrict__ rowp,
    const float* __restrict__ att, const float* __restrict__ bias,
    unsigned short* __restrict__ ahi, unsigned short* __restrict__ alo,
    float* __restrict__ hout, const int mode) {
  const int lane = threadIdx.x & 63;
  const int d = blockIdx.x * 4 + (threadIdx.x >> 6);   // 12500*4 = 50000 exact
  const int half = lane >> 5, sub = lane & 31;
  const int byteoff = half * 128 + sub * 4;            // 4B/lane covers 256B row
  const int choff = half * 64 + sub * 2;
  float o0 = 0.f, o1 = 0.f;
  #pragma unroll
  for (int t = 0; t < TT; ++t) {
    const char* xlt = (const char*)xl4 + (size_t)t * NN * 256;
    const char* xrt = (const char*)xr4 + (size_t)t * NN * 256;
    const int* colt = col + (size_t)t * EEN;
    float2 av = *(const float2*)(att + t * FD + choff);
    av.x *= LOG2E; av.y *= LOG2E;
    const float sa0 = sgn04(av.x), sa1 = sgn04(av.y);
    const unsigned int ur =
        *(const unsigned int*)(xrt + (size_t)d * 256 + byteoff);
    const float axr0 = av.x * blo(ur), axr1 = av.y * bhi(ur);
    float den = 0.f, ac0 = 0.f, ac1 = 0.f;
    const int beg = rowp[t * RPS + d];
    const int end = rowp[t * RPS + d + 1];   // deg >= 1 (self-loop)

    unsigned int xA[4], xB[4];
    // fetch batch at e0 into xv (cols clamped to end-1; waste is L1-hot)
    auto fetch = [&](int e0, unsigned int* xv) {
      int ci = e0 + (lane & 3);
      ci = (ci < end) ? ci : (end - 1);
      const int cvec = colt[ci];
      #pragma unroll
      for (int j = 0; j < 4; ++j) {
        const int c = __builtin_amdgcn_readlane(cvec, j);   // SGPR base
        xv[j] = *(const unsigned int*)(xlt + ((size_t)((unsigned)c << 8)) + byteoff);
      }
    };
    fetch(beg, xA);
    for (int e = beg; e < end; e += 4) {
      if (e + 4 < end) fetch(e + 4, xB);
      #pragma unroll
      for (int j = 0; j < 4; ++j) {
        const float x0 = blo(xA[j]), x1 = bhi(xA[j]);
        const float q0 = fmaf(av.x, x0, axr0), q1 = fmaf(av.y, x1, axr1);
        const float r = fmaf(sa1, fabsf(q1), sa0 * fabsf(q0));
        const float c = qsum32(fmaf(0.6f, q0 + q1, r));
        const float w = (e + j < end) ? fexp2(c) : 0.f;
        den += w;
        ac0 = fmaf(w, x0, ac0);
        ac1 = fmaf(w, x1, ac1);
      }
      #pragma unroll
      for (int j = 0; j < 4; ++j) xA[j] = xB[j];
    }
    const float rden = __builtin_amdgcn_rcpf(den);
    o0 = fmaf(ac0, rden, o0);
    o1 = fmaf(ac1, rden, o1);
  }
  #pragma unroll
  for (int t = 0; t < TT; ++t) {
    const float2 bv = *(const float2*)(bias + t * FD + choff);
    o0 += bv.x; o1 += bv.y;
  }
  if (mode == 0) {
    o0 = fmaxf(o0, 0.f); o1 = fmaxf(o1, 0.f);
    const unsigned short h0 = f2bf(o0), h1 = f2bf(o1);
    const unsigned short l0 = f2bf(o0 - bf2f(h0)), l1 = f2bf(o1 - bf2f(h1));
    *(unsigned int*)((char*)ahi + (size_t)d * 256 + byteoff) =
        (unsigned)h0 | ((unsigned)h1 << 16);
    *(unsigned int*)((char*)alo + (size_t)d * 256 + byteoff) =
        (unsigned)l0 | ((unsigned)l1 << 16);
  } else {
    *(float2*)(hout + (size_t)d * FD + choff) = make_float2(o0, o1);
  }
}

// ---------- MLP head (relu on h fused): thread per dst ----------
__global__ __launch_bounds__(256) void k_mlp(const float* __restrict__ h,
                                             const float* __restrict__ W1,
                                             const float* __restrict__ b1,
                                             const float* __restrict__ W2,
                                             const float* __restrict__ b2,
                                             float* __restrict__ out) {
  __shared__ float sW1[128 * 8];
  __shared__ float sW2[8 * 10];
  __shared__ float sb1[8], sb2[10];
  for (int i = threadIdx.x; i < 1024; i += 256) sW1[i] = W1[i];
  if (threadIdx.x < 80) sW2[threadIdx.x] = W2[threadIdx.x];
  if (threadIdx.x < 8)  sb1[threadIdx.x] = b1[threadIdx.x];
  if (threadIdx.x < 10) sb2[threadIdx.x] = b2[threadIdx.x];
  __syncthreads();
  const int n = blockIdx.x * 256 + threadIdx.x;
  if (n >= NN) return;
  const float* hn = h + (size_t)n * FD;
  float z[8];
  #pragma unroll
  for (int j = 0; j < 8; ++j) z[j] = sb1[j];
  for (int k = 0; k < FD; k += 4) {
    float4 hv = *(const float4*)(hn + k);
    hv.x = fmaxf(hv.x, 0.f); hv.y = fmaxf(hv.y, 0.f);
    hv.z = fmaxf(hv.z, 0.f); hv.w = fmaxf(hv.w, 0.f);
    #pragma unroll
    for (int j = 0; j < 8; ++j) {
      z[j] += hv.x * sW1[(k + 0) * 8 + j] + hv.y * sW1[(k + 1) * 8 + j]
            + hv.z * sW1[(k + 2) * 8 + j] + hv.w * sW1[(k + 3) * 8 + j];
    }
  }
  #pragma unroll
  for (int j = 0; j < 8; ++j) z[j] = fmaxf(z[j], 0.f);
  float o[10];
  #pragma unroll
  for (int c = 0; c < 10; ++c) o[c] = sb2[c];
  #pragma unroll
  for (int j = 0; j < 8; ++j)
    #pragma unroll
    for (int c = 0; c < 10; ++c) o[c] += z[j] * sW2[j * 10 + c];
  float* op = out + (size_t)n * 10;
  #pragma unroll
  for (int c = 0; c < 10; ++c) op[c] = o[c];
}

extern "C" void kernel_launch(void* const* d_in, const int* in_sizes, int n_in,
                              void* d_out, int out_size, void* d_ws, size_t ws_size,
                              hipStream_t stream) {
  const float* x    = (const float*)d_in[0];
  const int*   ei   = (const int*)d_in[1];
  const float* Wl1  = (const float*)d_in[2];
  const float* Wr1  = (const float*)d_in[3];
  const float* att1 = (const float*)d_in[4];
  const float* b1   = (const float*)d_in[5];
  const float* Wl2  = (const float*)d_in[6];
  const float* Wr2  = (const float*)d_in[7];
  const float* att2 = (const float*)d_in[8];
  const float* b2   = (const float*)d_in[9];
  const float* Wi1  = (const float*)d_in[10];
  const float* bi1  = (const float*)d_in[11];
  const float* Wi2  = (const float*)d_in[12];
  const float* bi2  = (const float*)d_in[13];
  float* out = (float*)d_out;

  char* ws = (char*)d_ws;
  size_t off = 0;
  auto alloc = [&](size_t bytes) {
    void* p = ws + off;
    off = (off + bytes + 255) & ~(size_t)255;
    return p;
  };
  unsigned short* xl4   = (unsigned short*)alloc((size_t)TT * NN * FD * 2); // 51.2 MB
  unsigned short* xr4   = (unsigned short*)alloc((size_t)TT * NN * FD * 2); // 51.2 MB
  unsigned short* Ahi   = (unsigned short*)alloc((size_t)NN * FD * 2);      // 12.8 MB
  unsigned short* Alo   = (unsigned short*)alloc((size_t)NN * FD * 2);      // 12.8 MB (contiguous)
  unsigned short* Bpack = (unsigned short*)alloc((size_t)2 * TT * 2 * 16384 * 2); // 0.5 MB
  int*            col   = (int*)alloc((size_t)TT * EEN * 4);                // 7.2 MB
  int*            rowp  = (int*)alloc((size_t)TT * RPS * 4);                // 0.8 MB
  int*            bcur  = (int*)alloc((size_t)TT * NBKT * 4);
  int*            bbase = (int*)alloc((size_t)TT * NBKT * 4);
  unsigned int*   ebuf  = (unsigned int*)alloc((size_t)TT * NBKT * BCAP * 4); // 12.85 MB
  // h2 (f32, 25.6 MB) aliases Ahi+Alo (both dead after layer-2 k_gemm4).
  float* h2 = (float*)Ahi;

  // --- CSR build (shared by both layers; self-loops included) ---
  hipMemsetAsync(bcur, 0, (size_t)TT * NBKT * 4, stream);
  k_cvtW<<<1024, 256, 0, stream>>>(Wl1, Wr1, Wl2, Wr2, Bpack);
  k_bucket<<<dim3(110, TT), 256, 0, stream>>>(ei, bcur, ebuf);
  k_bktscan<<<1, 1024, 0, stream>>>(bcur, bbase);
  k_scatter3<<<dim3(NBKT, TT), 256, 0, stream>>>(ebuf, bcur, bbase, rowp, col);

  // --- layer 1 ---
  k_cvtA<<<6250, 256, 0, stream>>>(x, Ahi, Alo);
  k_gemm4<<<dim3(782, TT), 128, 0, stream>>>(Ahi, Alo, Bpack, xl4, xr4);
  k_agg7<<<12500, 256, 0, stream>>>(xl4, xr4, col, rowp, att1, b1,
                                    Ahi, Alo, nullptr, 0);
  // --- layer 2 ---
  k_gemm4<<<dim3(782, TT), 128, 0, stream>>>(Ahi, Alo, Bpack + (size_t)TT * 2 * 16384,
                                             xl4, xr4);
  k_agg7<<<12500, 256, 0, stream>>>(xl4, xr4, col, rowp, att2, b2,
                                    nullptr, nullptr, h2, 1);
  // --- MLP head ---
  k_mlp<<<(NN + 255) / 256, 256, 0, stream>>>(h2, Wi1, bi1, Wi2, bi2, out);
}